// Round 4
// baseline (87.563 us; speedup 1.0000x reference)
//
#include <hip/hip_runtime.h>

#define B_TOT 16384
#define F_DIM 512
#define T_DIM 256
#define N_DIM 256
#define NBLK  2048

__device__ __forceinline__ float wave_sum(float v) {
#pragma unroll
    for (int o = 32; o; o >>= 1) v += __shfl_xor(v, o, 64);
    return v;
}
__device__ __forceinline__ float wave_prod(float v) {
#pragma unroll
    for (int o = 32; o; o >>= 1) v *= __shfl_xor(v, o, 64);
    return v;
}
__device__ __forceinline__ float lse2(float a, float b) {
    float m = fmaxf(a, b);
    return m + __logf(__expf(a - m) + __expf(b - m));
}

// Fused: per-row wave processing (as round 3) + last-block final reduction.
// Cross-block handoff uses agent-scope atomics (per-XCD L2s are not coherent;
// plain loads could serve stale lines from a previous graph replay).
__global__ __launch_bounds__(256, 4) void setcrit_fused(
    const float* __restrict__ pred_class,
    const float* __restrict__ pred_v,
    const float* __restrict__ targets,
    float* __restrict__ partial,
    unsigned int* __restrict__ ctr,
    float* __restrict__ out)
{
    __shared__ float s_predv[4][N_DIM];
    __shared__ float s_fin[4][4];
    __shared__ float s_red[4];
    __shared__ unsigned int s_ticket;

    const int tid = threadIdx.x;
    const int l   = tid & 63;
    const int w   = tid >> 6;
    const unsigned long long lt = (1ull << l) - 1ull;
    const int wave_id = blockIdx.x * 4 + w;   // 8192 waves, 2 rows each

    float acc_pick = 0.f, acc_dsq = 0.f, acc_multi = 0.f;
    int   acc_tc = 0;

#pragma unroll
    for (int i = 0; i < 2; ++i) {
        const int b = i * (NBLK * 4) + wave_id;
        const float* lgp = pred_class + (size_t)b * (2 * F_DIM);
        const float* pvp = pred_v     + (size_t)b * N_DIM;
        const float* tgp = targets    + (size_t)b * T_DIM;

        // ---- issue all row loads up front (independent, coalesced) ----
        float4 g0 = *(const float4*)(lgp + 8 * l);          // f = 4l, 4l+1
        float4 g1 = *(const float4*)(lgp + 8 * l + 4);      // f = 4l+2, 4l+3
        float4 g2 = *(const float4*)(lgp + 512 + 8 * l);    // f = 256+4l, 257+4l
        float4 g3 = *(const float4*)(lgp + 512 + 8 * l + 4);// f = 258+4l, 259+4l
        float4 pv = *(const float4*)(pvp + 4 * l);          // n = 4l..4l+3
        float4 tg = *(const float4*)(tgp + 4 * l);          // t = 4l..4l+3

        *(float4*)(&s_predv[w][4 * l]) = pv;                // stage for gather

        // ---- log-softmax picks: f<256 -> logp[1], f>=256 -> logp[0] ----
        float p = 0.f;
        p += g0.y - lse2(g0.x, g0.y);
        p += g0.w - lse2(g0.z, g0.w);
        p += g1.y - lse2(g1.x, g1.y);
        p += g1.w - lse2(g1.z, g1.w);
        p += g2.x - lse2(g2.x, g2.y);
        p += g2.z - lse2(g2.z, g2.w);
        p += g3.x - lse2(g3.x, g3.y);
        p += g3.z - lse2(g3.z, g3.w);
        acc_pick += p;

        // ---- mask + exclusive prefix over t=4l..4l+3 via 4 ballots ----
        bool m0 = g0.y > g0.x;
        bool m1 = g0.w > g0.z;
        bool m2 = g1.y > g1.x;
        bool m3 = g1.w > g1.z;
        unsigned long long b0 = __ballot(m0);
        unsigned long long b1 = __ballot(m1);
        unsigned long long b2 = __ballot(m2);
        unsigned long long b3 = __ballot(m3);

        int e0 = __popcll(b0 & lt) + __popcll(b1 & lt)
               + __popcll(b2 & lt) + __popcll(b3 & lt);
        int e1 = e0 + (m0 ? 1 : 0);
        int e2 = e1 + (m1 ? 1 : 0);
        int e3 = e2 + (m2 ? 1 : 0);
        acc_tc += __popcll(b0) + __popcll(b1) + __popcll(b2) + __popcll(b3);

        // ---- matched gather + squared error (tc==0 rows contribute 0) ----
        float dsq = 0.f, d;
        if (m0) { d = s_predv[w][e0] - tg.x; dsq += d * d; }
        if (m1) { d = s_predv[w][e1] - tg.y; dsq += d * d; }
        if (m2) { d = s_predv[w][e2] - tg.z; dsq += d * d; }
        if (m3) { d = s_predv[w][e3] - tg.w; dsq += d * d; }
        acc_dsq += dsq;

        // ---- product over the row ----
        float prod = wave_prod(pv.x * pv.y * pv.z * pv.w);
        float pm1 = prod - 1.f;
        acc_multi += pm1 * pm1;
    }

    float pickS = wave_sum(acc_pick);
    float dsqS  = wave_sum(acc_dsq);
    if (l == 0) {
        s_fin[w][0] = pickS;
        s_fin[w][1] = acc_multi;
        s_fin[w][2] = dsqS;
        s_fin[w][3] = (float)acc_tc;
    }
    __syncthreads();

    if (tid == 0) {
        float v0 = 0.f, v1 = 0.f, v2 = 0.f, v3 = 0.f;
#pragma unroll
        for (int k = 0; k < 4; ++k) {
            v0 += s_fin[k][0]; v1 += s_fin[k][1];
            v2 += s_fin[k][2]; v3 += s_fin[k][3];
        }
        // agent-scope stores: globally visible past this XCD's L2
        __hip_atomic_store(&partial[0 * NBLK + blockIdx.x], v0,
                           __ATOMIC_RELAXED, __HIP_MEMORY_SCOPE_AGENT);
        __hip_atomic_store(&partial[1 * NBLK + blockIdx.x], v1,
                           __ATOMIC_RELAXED, __HIP_MEMORY_SCOPE_AGENT);
        __hip_atomic_store(&partial[2 * NBLK + blockIdx.x], v2 * (1.f / (float)T_DIM),
                           __ATOMIC_RELAXED, __HIP_MEMORY_SCOPE_AGENT);
        __hip_atomic_store(&partial[3 * NBLK + blockIdx.x], v3 * (1.f / (float)T_DIM),
                           __ATOMIC_RELAXED, __HIP_MEMORY_SCOPE_AGENT);
        // release + ticket
        s_ticket = __hip_atomic_fetch_add(ctr, 1u,
                           __ATOMIC_ACQ_REL, __HIP_MEMORY_SCOPE_AGENT);
    }
    __syncthreads();

    if (s_ticket == NBLK - 1) {
        // last block to finish: deterministic final reduction (fixed order)
        float v = 0.f;
#pragma unroll
        for (int i = 0; i < NBLK / 64; ++i)
            v += __hip_atomic_load(&partial[w * NBLK + i * 64 + l],
                                   __ATOMIC_RELAXED, __HIP_MEMORY_SCOPE_AGENT);
        v = wave_sum(v);
        if (l == 0) s_red[w] = v;
        __syncthreads();

        if (tid == 0) {
            float loss_label = -s_red[0] / ((float)B_TOT * (float)F_DIM);
            float loss_multi = s_red[1] / (float)B_TOT;
            float loss_true  = s_red[2] / (float)B_TOT;
            float f1         = s_red[3] / (float)B_TOT;
            float r = loss_multi + loss_true;
            out[0] = loss_label + r;
            out[1] = loss_label;
            out[2] = r;
            out[3] = loss_multi;
            out[4] = loss_true;
            out[5] = f1;
        }
    }
}

extern "C" void kernel_launch(void* const* d_in, const int* in_sizes, int n_in,
                              void* d_out, int out_size, void* d_ws, size_t ws_size,
                              hipStream_t stream) {
    const float* pred_class = (const float*)d_in[0];
    const float* pred_v     = (const float*)d_in[1];
    const float* targets    = (const float*)d_in[2];

    float* partial = (float*)d_ws;                        // 4*NBLK floats = 32 KB
    unsigned int* ctr = (unsigned int*)((char*)d_ws + 4 * NBLK * sizeof(float));

    hipMemsetAsync(ctr, 0, sizeof(unsigned int), stream); // reset ticket each call
    setcrit_fused<<<NBLK, 256, 0, stream>>>(pred_class, pred_v, targets,
                                            partial, ctr, (float*)d_out);
}